// Round 4
// baseline (364.851 us; speedup 1.0000x reference)
//
#include <hip/hip_runtime.h>
#include <math.h>

typedef __attribute__((ext_vector_type(8))) short bf16x8;
typedef __attribute__((ext_vector_type(4))) float f32x4;
typedef __attribute__((ext_vector_type(2))) float f32x2;
typedef __attribute__((ext_vector_type(4))) unsigned int uint32x4;
typedef __attribute__((ext_vector_type(2))) unsigned int uint32x2;
typedef unsigned int uint32;
typedef unsigned short ushort;

#define N_NODES 10000
#define E_EDGES 100000
#define T_TRI   200000
#define NORB    9
#define H_DIM   128
#define C_DIM   64
#define USTR    36   // LDS row stride in uint32 (even, mult of 4: b64/b128-aligned)

__device__ __forceinline__ ushort f2b_rtne(float f) {
  uint32 u = __float_as_uint(f);
  u += 0x7FFFu + ((u >> 16) & 1u);
  return (ushort)(u >> 16);
}
__device__ __forceinline__ uint32 rtne2(float a, float b) {  // low=a, high=b
  uint32 ua = __float_as_uint(a), ub = __float_as_uint(b);
  ua += 0x7FFFu + ((ua >> 16) & 1u);
  ub += 0x7FFFu + ((ub >> 16) & 1u);
  return (ua >> 16) | (ub & 0xFFFF0000u);
}
__device__ __forceinline__ uint32 trunc2(float a, float b) {
  return (__float_as_uint(a) >> 16) | (__float_as_uint(b) & 0xFFFF0000u);
}
__device__ __forceinline__ float b2f(ushort u) {
  return __uint_as_float(((uint32)u) << 16);
}
__device__ __forceinline__ float silu_f(float x) {
  return x * __builtin_amdgcn_rcpf(1.0f + __expf(-x));
}
__device__ __forceinline__ float sigmoid_f(float x) {
  return __builtin_amdgcn_rcpf(1.0f + __expf(-x));
}
__device__ __forceinline__ float rl(float v, int k) {
  return __uint_as_float(__builtin_amdgcn_readlane(__float_as_uint(v), k));
}
__device__ __forceinline__ f32x4 mfma16(bf16x8 a, bf16x8 b, f32x4 c) {
  return __builtin_amdgcn_mfma_f32_16x16x32_bf16(a, b, c, 0, 0, 0);
}
#define LDS_FENCE() asm volatile("s_waitcnt lgkmcnt(0)" ::: "memory")

// trunc-pack 8 consecutive f32 (16B-aligned) into a bf16x8 frag
__device__ __forceinline__ bf16x8 pack8(const float* p) {
  f32x4 v0 = *(const f32x4*)p;
  f32x4 v1 = *(const f32x4*)(p + 4);
  uint32x4 u;
  u[0] = trunc2(v0[0], v0[1]);
  u[1] = trunc2(v0[2], v0[3]);
  u[2] = trunc2(v1[0], v1[1]);
  u[3] = trunc2(v1[2], v1[3]);
  return __builtin_bit_cast(bf16x8, u);
}
__device__ __forceinline__ bf16x8 pack8v(f32x4 v0, f32x4 v1) {
  uint32x4 u;
  u[0] = trunc2(v0[0], v0[1]);
  u[1] = trunc2(v0[2], v0[3]);
  u[2] = trunc2(v1[0], v1[1]);
  u[3] = trunc2(v1[2], v1[3]);
  return __builtin_bit_cast(bf16x8, u);
}
// Weight frag for W[64][64] row-major: lane holds W[kt*32+g*8+b][ct*16+l15].
// Used as MFMA *A*-operand it represents (W^T) tile (m-tile=ct, k-tile=kt).
__device__ __forceinline__ bf16x8 bfrag_w(const float* W, int kt, int ct, int lane) {
  const float* p = W + (size_t)(kt * 32 + ((lane >> 4) * 8)) * 64 + ct * 16 + (lane & 15);
  bf16x8 r;
#pragma unroll
  for (int b = 0; b < 8; ++b) r[b] = (short)f2b_rtne(p[(size_t)b * 64]);
  return r;
}

// K1: h = x @ w_node + b_node ; x1b = bf16(h[:,:64]); sigxkb = bf16(sigmoid(h[:,64:]))
__global__ __launch_bounds__(128) void k_node_mlp(
    const float* __restrict__ x, const float* __restrict__ w_node,
    const float* __restrict__ b_node, ushort* __restrict__ x1b,
    ushort* __restrict__ sigxkb) {
  __shared__ float xs[H_DIM];
  int n = blockIdx.x;
  int c = threadIdx.x;
  xs[c] = x[(size_t)n * H_DIM + c];
  __syncthreads();
  float acc = b_node[c];
#pragma unroll 8
  for (int k = 0; k < H_DIM; ++k)
    acc = fmaf(xs[k], w_node[k * H_DIM + c], acc);
  if (c < C_DIM)
    x1b[(size_t)n * C_DIM + c] = f2b_rtne(acc);
  else
    sigxkb[(size_t)n * C_DIM + (c - C_DIM)] = f2b_rtne(sigmoid_f(acc));
}

// K2: per 16-edge block: cji2 = silu(silu(cji@w_c1)@w_c2) (bf16 out) AND
//     rbsum[e,h] = sum_d rb_w[e,d]*cji2[e,d,h] (f32 out). Swapped-operand MFMA:
//     lane holds data-row l15, output cols ct*16+4g+r.
__global__ __launch_bounds__(256) void k_cji_fused(
    const float* __restrict__ cji, const float* __restrict__ w_c1,
    const float* __restrict__ w_c2, const float* __restrict__ rb,
    const float* __restrict__ cutoff_w, ushort* __restrict__ cji2,
    float* __restrict__ rbsum) {
  __shared__ uint32 lds_all[4][2][16 * USTR];
  int lane = threadIdx.x & 63;
  int l15 = lane & 15, g = lane >> 4;
  uint32* lds0 = lds_all[threadIdx.x >> 6][0];
  uint32* lds1 = lds_all[threadIdx.x >> 6][1];
  int wid = (blockIdx.x * 256 + (int)threadIdx.x) >> 6;
  int nw = (gridDim.x * 256) >> 6;
  bf16x8 w1f[2][4], w2f[2][4];
#pragma unroll
  for (int kt = 0; kt < 2; ++kt)
#pragma unroll
    for (int ct = 0; ct < 4; ++ct) {
      w1f[kt][ct] = bfrag_w(w_c1, kt, ct, lane);
      w2f[kt][ct] = bfrag_w(w_c2, kt, ct, lane);
    }
  uint32* cji2u = (uint32*)cji2;
  const int nblk = E_EDGES / 16;  // 6250
  f32x4 z = {0.f, 0.f, 0.f, 0.f};
  for (int eb = wid; eb < nblk; eb += nw) {
    int e0 = eb * 16;
    int myrow0 = 9 * (e0 + l15);           // this lane's edge's first cji row
    float cw = cutoff_w[e0 + l15];
    f32x4 rs[4];                            // rbsum accum: rs[ct][r]
#pragma unroll
    for (int ct = 0; ct < 4; ++ct) rs[ct] = z;
    // prefetch d=0
    const float* ap = cji + (size_t)myrow0 * 64 + g * 8;
    f32x4 nv0 = *(const f32x4*)ap;
    f32x4 nv1 = *(const f32x4*)(ap + 4);
    f32x4 nv2 = *(const f32x4*)(ap + 32);
    f32x4 nv3 = *(const f32x4*)(ap + 36);
#pragma unroll
    for (int d = 0; d < NORB; ++d) {
      f32x4 c0 = nv0, c1 = nv1, c2 = nv2, c3 = nv3;
      if (d < NORB - 1) {                   // hoist next-d global loads
        const float* np = cji + (size_t)(myrow0 + d + 1) * 64 + g * 8;
        nv0 = *(const f32x4*)np;
        nv1 = *(const f32x4*)(np + 4);
        nv2 = *(const f32x4*)(np + 32);
        nv3 = *(const f32x4*)(np + 36);
      }
      bf16x8 a0 = pack8v(c0, c1), a1 = pack8v(c2, c3);
      uint32* buf = (d & 1) ? lds1 : lds0;
      // layer 1 (swapped): D^T frag, lane -> row l15, cols ct*16+4g+r
#pragma unroll
      for (int ct = 0; ct < 4; ++ct) {
        f32x4 acc = mfma16(w1f[0][ct], a0, z);
        acc = mfma16(w1f[1][ct], a1, acc);
        uint32x2 p;
        p[0] = rtne2(silu_f(acc[0]), silu_f(acc[1]));
        p[1] = rtne2(silu_f(acc[2]), silu_f(acc[3]));
        *(uint32x2*)(buf + l15 * USTR + ct * 8 + 2 * g) = p;
      }
      LDS_FENCE();
      bf16x8 t0 = *(const bf16x8*)(buf + l15 * USTR + 4 * g);
      bf16x8 t1 = *(const bf16x8*)(buf + l15 * USTR + 16 + 4 * g);
      float rbw = rb[(e0 + l15) * NORB + d] * cw;
      int rowu = (myrow0 + d) * 32;  // uint32 offset of this row in cji2
#pragma unroll
      for (int ct = 0; ct < 4; ++ct) {
        f32x4 acc = mfma16(w2f[0][ct], t0, z);
        acc = mfma16(w2f[1][ct], t1, acc);
        float v0 = silu_f(acc[0]), v1 = silu_f(acc[1]);
        float v2 = silu_f(acc[2]), v3 = silu_f(acc[3]);
        uint32x2 p;
        p[0] = rtne2(v0, v1);
        p[1] = rtne2(v2, v3);
        *(uint32x2*)(cji2u + rowu + ct * 8 + 2 * g) = p;
        rs[ct][0] = fmaf(rbw, v0, rs[ct][0]);
        rs[ct][1] = fmaf(rbw, v1, rs[ct][1]);
        rs[ct][2] = fmaf(rbw, v2, rs[ct][2]);
        rs[ct][3] = fmaf(rbw, v3, rs[ct][3]);
      }
    }
    float* rp = rbsum + (size_t)(e0 + l15) * 64 + 4 * g;
#pragma unroll
    for (int ct = 0; ct < 4; ++ct) {
      f32x2 q0 = {rs[ct][0], rs[ct][1]}, q1 = {rs[ct][2], rs[ct][3]};
      *(f32x2*)(rp + ct * 16) = q0;
      *(f32x2*)(rp + ct * 16 + 2) = q1;
    }
  }
}

// K3: per-triplet gather + normalize + gate + atomic segment-sum
__global__ __launch_bounds__(256) void k_triplet(
    const ushort* __restrict__ cji2, const float* __restrict__ rb,
    const float* __restrict__ cutoff_w, const float* __restrict__ shb,
    const int* __restrict__ tri_idx_k, const int* __restrict__ edge_idx_kj,
    const int* __restrict__ edge_idx_ji, const ushort* __restrict__ sigxkb,
    float* __restrict__ agg) {
  int lane = threadIdx.x & 63;
  int wid = (blockIdx.x * 256 + (int)threadIdx.x) >> 6;
  int nw = (gridDim.x * 256) >> 6;
  for (int t = wid; t < T_TRI; t += nw) {
    int e = edge_idx_kj[t];
    float cw = cutoff_w[e];
    const ushort* crow = cji2 + (size_t)e * (NORB * C_DIM);
    float acc = 0.f;
#pragma unroll
    for (int d = 0; d < NORB; ++d) {
      float coeff = rb[e * NORB + d] * cw * shb[t * NORB + d];
      acc = fmaf(coeff, b2f(crow[d * C_DIM + lane]), acc);
    }
    float s = acc * acc;
#pragma unroll
    for (int m = 32; m >= 1; m >>= 1) s += __shfl_xor(s, m, 64);
    float scale = __builtin_amdgcn_rsqf(fmaxf(s, 1e-30f));
    int kn = tri_idx_k[t];
    float gxe = b2f(sigxkb[(size_t)kn * C_DIM + lane]);
    float val = acc * scale * gxe;
    int ej = edge_idx_ji[t];
    atomicAdd(&agg[(size_t)ej * C_DIM + lane], val);
  }
}

// K45: tbw = silu(silu(agg@w_t1+b_t1)@w_t2+b_t2) (in-reg);
//      lcao = normalize(rbsum*(1+tbw)) @ w_basis. Swapped-operand MFMA.
__global__ __launch_bounds__(256) void k_tbw_lcao(
    const float* __restrict__ agg, const float* __restrict__ w_t1,
    const float* __restrict__ b_t1, const float* __restrict__ w_t2,
    const float* __restrict__ b_t2, const float* __restrict__ rbsum,
    const float* __restrict__ w_basis, float* __restrict__ lcao) {
  __shared__ uint32 lds_all[4][2][16 * USTR];
  int lane = threadIdx.x & 63;
  int l15 = lane & 15, g = lane >> 4;
  uint32* lds0 = lds_all[threadIdx.x >> 6][0];
  uint32* lds1 = lds_all[threadIdx.x >> 6][1];
  int wid = (blockIdx.x * 256 + (int)threadIdx.x) >> 6;
  int nw = (gridDim.x * 256) >> 6;
  bf16x8 wt1[2][4], wt2[2][4], wb[2][4];
  float bt1v[4][4], bt2v[4][4];
#pragma unroll
  for (int ct = 0; ct < 4; ++ct) {
#pragma unroll
    for (int r = 0; r < 4; ++r) {
      bt1v[ct][r] = b_t1[ct * 16 + 4 * g + r];
      bt2v[ct][r] = b_t2[ct * 16 + 4 * g + r];
    }
#pragma unroll
    for (int kt = 0; kt < 2; ++kt) {
      wt1[kt][ct] = bfrag_w(w_t1, kt, ct, lane);
      wt2[kt][ct] = bfrag_w(w_t2, kt, ct, lane);
      wb[kt][ct] = bfrag_w(w_basis, kt, ct, lane);
    }
  }
  const int nblk = E_EDGES / 16;
  f32x4 z = {0.f, 0.f, 0.f, 0.f};
  for (int eb = wid; eb < nblk; eb += nw) {
    int e0 = eb * 16;
    const float* ap = agg + (size_t)(e0 + l15) * 64 + g * 8;
    bf16x8 a0 = pack8(ap), a1 = pack8(ap + 32);
    // layer 1 -> LDS (buf0)
#pragma unroll
    for (int ct = 0; ct < 4; ++ct) {
      f32x4 acc = mfma16(wt1[0][ct], a0, z);
      acc = mfma16(wt1[1][ct], a1, acc);
      uint32x2 p;
      p[0] = rtne2(silu_f(acc[0] + bt1v[ct][0]), silu_f(acc[1] + bt1v[ct][1]));
      p[1] = rtne2(silu_f(acc[2] + bt1v[ct][2]), silu_f(acc[3] + bt1v[ct][3]));
      *(uint32x2*)(lds0 + l15 * USTR + ct * 8 + 2 * g) = p;
    }
    LDS_FENCE();
    bf16x8 t0 = *(const bf16x8*)(lds0 + l15 * USTR + 4 * g);
    bf16x8 t1 = *(const bf16x8*)(lds0 + l15 * USTR + 16 + 4 * g);
    // layer 2 -> tbw in regs; gate rbsum; accumulate ss
    const float* rp = rbsum + (size_t)(e0 + l15) * 64 + 4 * g;
    f32x4 val[4];
    float ss = 0.f;
#pragma unroll
    for (int ct = 0; ct < 4; ++ct) {
      f32x4 acc = mfma16(wt2[0][ct], t0, z);
      acc = mfma16(wt2[1][ct], t1, acc);
      f32x2 q0 = *(const f32x2*)(rp + ct * 16);
      f32x2 q1 = *(const f32x2*)(rp + ct * 16 + 2);
      val[ct][0] = q0[0] * (1.0f + silu_f(acc[0] + bt2v[ct][0]));
      val[ct][1] = q0[1] * (1.0f + silu_f(acc[1] + bt2v[ct][1]));
      val[ct][2] = q1[0] * (1.0f + silu_f(acc[2] + bt2v[ct][2]));
      val[ct][3] = q1[1] * (1.0f + silu_f(acc[3] + bt2v[ct][3]));
      ss += val[ct][0] * val[ct][0] + val[ct][1] * val[ct][1] +
            val[ct][2] * val[ct][2] + val[ct][3] * val[ct][3];
    }
    ss += __shfl_xor(ss, 16, 64);
    ss += __shfl_xor(ss, 32, 64);
    float scale = __builtin_amdgcn_rsqf(fmaxf(ss, 1e-30f));
    // normalized row -> LDS (buf1) as bf16 B-frag
#pragma unroll
    for (int ct = 0; ct < 4; ++ct) {
      uint32x2 p;
      p[0] = rtne2(val[ct][0] * scale, val[ct][1] * scale);
      p[1] = rtne2(val[ct][2] * scale, val[ct][3] * scale);
      *(uint32x2*)(lds1 + l15 * USTR + ct * 8 + 2 * g) = p;
    }
    LDS_FENCE();
    bf16x8 n0 = *(const bf16x8*)(lds1 + l15 * USTR + 4 * g);
    bf16x8 n1 = *(const bf16x8*)(lds1 + l15 * USTR + 16 + 4 * g);
    float* lp = lcao + (size_t)(e0 + l15) * 64 + 4 * g;
#pragma unroll
    for (int ct = 0; ct < 4; ++ct) {
      f32x4 o = mfma16(wb[0][ct], n0, z);
      o = mfma16(wb[1][ct], n1, o);
      f32x2 q0 = {o[0], o[1]}, q1 = {o[2], o[3]};
      *(f32x2*)(lp + ct * 16) = q0;
      *(f32x2*)(lp + ct * 16 + 2) = q1;
    }
  }
}

// K6: fnode = silu(silu([x1_i,x1_j]@w_n1+b_n1)@w_n2+b_n2);
//     msg = lcao*fnode; atomic scatter into nodeagg[idx_i].
__global__ __launch_bounds__(256) void k_msg_mfma(
    const ushort* __restrict__ x1b, const int* __restrict__ idx_i,
    const int* __restrict__ idx_j, const float* __restrict__ w_n1,
    const float* __restrict__ b_n1, const float* __restrict__ w_n2,
    const float* __restrict__ b_n2, const float* __restrict__ lcao,
    float* __restrict__ nodeagg) {
  __shared__ uint32 lds_all[4][16 * USTR];
  int lane = threadIdx.x & 63;
  int l15 = lane & 15, g = lane >> 4;
  uint32* lds = lds_all[threadIdx.x >> 6];
  int wid = (blockIdx.x * 256 + (int)threadIdx.x) >> 6;
  int nw = (gridDim.x * 256) >> 6;
  bf16x8 wn1f[4][4], wn2f[2][4];
  float bn1v[4][4], bn2v[4][4];
#pragma unroll
  for (int ct = 0; ct < 4; ++ct) {
#pragma unroll
    for (int r = 0; r < 4; ++r) {
      bn1v[ct][r] = b_n1[ct * 16 + 4 * g + r];
      bn2v[ct][r] = b_n2[ct * 16 + 4 * g + r];
    }
#pragma unroll
    for (int kt = 0; kt < 4; ++kt) {
      const float* p = w_n1 + (size_t)(kt * 32 + g * 8) * 64 + ct * 16 + l15;
      bf16x8 r8;
#pragma unroll
      for (int b = 0; b < 8; ++b) r8[b] = (short)f2b_rtne(p[(size_t)b * 64]);
      wn1f[kt][ct] = r8;
    }
#pragma unroll
    for (int kt = 0; kt < 2; ++kt) wn2f[kt][ct] = bfrag_w(w_n2, kt, ct, lane);
  }
  const int nblk = E_EDGES / 16;
  f32x4 z = {0.f, 0.f, 0.f, 0.f};
  for (int eb = wid; eb < nblk; eb += nw) {
    int er = eb * 16 + l15;
    int ii = idx_i[er], jj = idx_j[er];
    const uint32x4* pi = (const uint32x4*)(x1b + (size_t)ii * 64 + g * 8);
    const uint32x4* pj = (const uint32x4*)(x1b + (size_t)jj * 64 + g * 8);
    bf16x8 a0 = __builtin_bit_cast(bf16x8, pi[0]);
    bf16x8 a1 = __builtin_bit_cast(bf16x8, pi[2]);
    bf16x8 a2 = __builtin_bit_cast(bf16x8, pj[0]);
    bf16x8 a3 = __builtin_bit_cast(bf16x8, pj[2]);
#pragma unroll
    for (int ct = 0; ct < 4; ++ct) {
      f32x4 acc = mfma16(wn1f[0][ct], a0, z);
      acc = mfma16(wn1f[1][ct], a1, acc);
      acc = mfma16(wn1f[2][ct], a2, acc);
      acc = mfma16(wn1f[3][ct], a3, acc);
      uint32x2 p;
      p[0] = rtne2(silu_f(acc[0] + bn1v[ct][0]), silu_f(acc[1] + bn1v[ct][1]));
      p[1] = rtne2(silu_f(acc[2] + bn1v[ct][2]), silu_f(acc[3] + bn1v[ct][3]));
      *(uint32x2*)(lds + l15 * USTR + ct * 8 + 2 * g) = p;
    }
    LDS_FENCE();
    bf16x8 t0 = *(const bf16x8*)(lds + l15 * USTR + 4 * g);
    bf16x8 t1 = *(const bf16x8*)(lds + l15 * USTR + 16 + 4 * g);
    LDS_FENCE();
    const float* lp = lcao + (size_t)er * 64 + 4 * g;
    float* np = nodeagg + (size_t)ii * 64 + 4 * g;
#pragma unroll
    for (int ct = 0; ct < 4; ++ct) {
      f32x4 acc = mfma16(wn2f[0][ct], t0, z);
      acc = mfma16(wn2f[1][ct], t1, acc);
      f32x2 q0 = *(const f32x2*)(lp + ct * 16);
      f32x2 q1 = *(const f32x2*)(lp + ct * 16 + 2);
      atomicAdd(np + ct * 16 + 0, q0[0] * silu_f(acc[0] + bn2v[ct][0]));
      atomicAdd(np + ct * 16 + 1, q0[1] * silu_f(acc[1] + bn2v[ct][1]));
      atomicAdd(np + ct * 16 + 2, q1[0] * silu_f(acc[2] + bn2v[ct][2]));
      atomicAdd(np + ct * 16 + 3, q1[1] * silu_f(acc[3] + bn2v[ct][3]));
    }
  }
}

// K7: out = x + nodeagg @ w_out
__global__ __launch_bounds__(256) void k_out(
    const float* __restrict__ x, const float* __restrict__ nodeagg,
    const float* __restrict__ w_out, float* __restrict__ out) {
  int lane = threadIdx.x & 63;
  int wid = (blockIdx.x * 256 + (int)threadIdx.x) >> 6;
  int nw = (gridDim.x * 256) >> 6;
  float wo0[64], wo1[64];
#pragma unroll
  for (int k = 0; k < 64; ++k) wo0[k] = w_out[k * H_DIM + lane];
#pragma unroll
  for (int k = 0; k < 64; ++k) wo1[k] = w_out[k * H_DIM + 64 + lane];
  for (int n = wid; n < N_NODES; n += nw) {
    float v = nodeagg[(size_t)n * 64 + lane];
    float a0 = 0.f, a1 = 0.f;
#pragma unroll
    for (int k = 0; k < 64; ++k) {
      float a = rl(v, k);
      a0 = fmaf(a, wo0[k], a0);
      a1 = fmaf(a, wo1[k], a1);
    }
    out[(size_t)n * H_DIM + lane] = x[(size_t)n * H_DIM + lane] + a0;
    out[(size_t)n * H_DIM + 64 + lane] = x[(size_t)n * H_DIM + 64 + lane] + a1;
  }
}

extern "C" void kernel_launch(void* const* d_in, const int* in_sizes, int n_in,
                              void* d_out, int out_size, void* d_ws, size_t ws_size,
                              hipStream_t stream) {
  const float* x         = (const float*)d_in[0];
  const float* cji       = (const float*)d_in[1];
  const float* cutoff_w  = (const float*)d_in[2];
  const float* rb        = (const float*)d_in[3];
  const float* shb       = (const float*)d_in[4];
  const int*   idx_i     = (const int*)d_in[5];
  const int*   idx_j     = (const int*)d_in[6];
  const int*   tri_idx_k = (const int*)d_in[7];
  const int*   e_kj      = (const int*)d_in[8];
  const int*   e_ji      = (const int*)d_in[9];
  const float* w_node    = (const float*)d_in[10];
  const float* b_node    = (const float*)d_in[11];
  const float* w_c1      = (const float*)d_in[12];
  const float* w_c2      = (const float*)d_in[13];
  const float* w_t1      = (const float*)d_in[14];
  const float* b_t1      = (const float*)d_in[15];
  const float* w_t2      = (const float*)d_in[16];
  const float* b_t2      = (const float*)d_in[17];
  const float* w_basis   = (const float*)d_in[18];
  const float* w_n1      = (const float*)d_in[19];
  const float* b_n1      = (const float*)d_in[20];
  const float* w_n2      = (const float*)d_in[21];
  const float* b_n2      = (const float*)d_in[22];
  const float* w_out     = (const float*)d_in[23];
  float* out = (float*)d_out;

  char* ws = (char*)d_ws;
  ushort* x1b    = (ushort*)(ws + 0);            //   1,280,000 B
  ushort* sigxkb = (ushort*)(ws + 1280000);      //   1,280,000 B
  ushort* cji2   = (ushort*)(ws + 2560000);      // 115,200,000 B
  float*  aggbuf = (float*)(ws + 117760000);     //  25,600,000 B
  float*  rbsum  = (float*)(ws + 143360000);     //  25,600,000 B
  float*  lcao   = (float*)(ws + 168960000);     //  25,600,000 B
  float*  nodeagg= (float*)(ws + 194560000);     //   2,560,000 B

  hipMemsetAsync(aggbuf, 0, (size_t)6400000 * sizeof(float), stream);
  hipMemsetAsync(nodeagg, 0, (size_t)640000 * sizeof(float), stream);

  k_node_mlp<<<N_NODES, 128, 0, stream>>>(x, w_node, b_node, x1b, sigxkb);
  k_cji_fused<<<1568, 256, 0, stream>>>(cji, w_c1, w_c2, rb, cutoff_w, cji2,
                                        rbsum);
  k_triplet<<<2048, 256, 0, stream>>>(cji2, rb, cutoff_w, shb, tri_idx_k, e_kj,
                                      e_ji, sigxkb, aggbuf);
  k_tbw_lcao<<<392, 256, 0, stream>>>(aggbuf, w_t1, b_t1, w_t2, b_t2, rbsum,
                                      w_basis, lcao);
  k_msg_mfma<<<1024, 256, 0, stream>>>(x1b, idx_i, idx_j, w_n1, b_n1, w_n2,
                                       b_n2, lcao, nodeagg);
  k_out<<<256, 256, 0, stream>>>(x, nodeagg, w_out, out);
}

// Round 5
// 352.650 us; speedup vs baseline: 1.0346x; 1.0346x over previous
//
#include <hip/hip_runtime.h>
#include <math.h>

typedef __attribute__((ext_vector_type(8))) short bf16x8;
typedef __attribute__((ext_vector_type(4))) float f32x4;
typedef __attribute__((ext_vector_type(2))) float f32x2;
typedef __attribute__((ext_vector_type(4))) unsigned int uint32x4;
typedef __attribute__((ext_vector_type(2))) unsigned int uint32x2;
typedef unsigned int uint32;
typedef unsigned short ushort;

#define N_NODES 10000
#define E_EDGES 100000
#define T_TRI   200000
#define NORB    9
#define H_DIM   128
#define C_DIM   64
#define USTR    36   // LDS row stride in uint32: b128-aligned, 2-way banks only

__device__ __forceinline__ ushort f2b_rtne(float f) {
  uint32 u = __float_as_uint(f);
  u += 0x7FFFu + ((u >> 16) & 1u);
  return (ushort)(u >> 16);
}
__device__ __forceinline__ uint32 rtne2(float a, float b) {  // low=a, high=b
  uint32 ua = __float_as_uint(a), ub = __float_as_uint(b);
  ua += 0x7FFFu + ((ua >> 16) & 1u);
  ub += 0x7FFFu + ((ub >> 16) & 1u);
  return (ua >> 16) | (ub & 0xFFFF0000u);
}
__device__ __forceinline__ uint32 trunc2(float a, float b) {
  return (__float_as_uint(a) >> 16) | (__float_as_uint(b) & 0xFFFF0000u);
}
__device__ __forceinline__ float b2f(ushort u) {
  return __uint_as_float(((uint32)u) << 16);
}
__device__ __forceinline__ float silu_f(float x) {
  return x * __builtin_amdgcn_rcpf(1.0f + __expf(-x));
}
__device__ __forceinline__ float sigmoid_f(float x) {
  return __builtin_amdgcn_rcpf(1.0f + __expf(-x));
}
__device__ __forceinline__ float rl(float v, int k) {
  return __uint_as_float(__builtin_amdgcn_readlane(__float_as_uint(v), k));
}
__device__ __forceinline__ f32x4 mfma16(bf16x8 a, bf16x8 b, f32x4 c) {
  return __builtin_amdgcn_mfma_f32_16x16x32_bf16(a, b, c, 0, 0, 0);
}
#define LDS_FENCE() asm volatile("s_waitcnt lgkmcnt(0)" ::: "memory")

__device__ __forceinline__ bf16x8 pack8(const float* p) {
  f32x4 v0 = *(const f32x4*)p;
  f32x4 v1 = *(const f32x4*)(p + 4);
  uint32x4 u;
  u[0] = trunc2(v0[0], v0[1]);
  u[1] = trunc2(v0[2], v0[3]);
  u[2] = trunc2(v1[0], v1[1]);
  u[3] = trunc2(v1[2], v1[3]);
  return __builtin_bit_cast(bf16x8, u);
}
__device__ __forceinline__ bf16x8 pack8v(f32x4 v0, f32x4 v1) {
  uint32x4 u;
  u[0] = trunc2(v0[0], v0[1]);
  u[1] = trunc2(v0[2], v0[3]);
  u[2] = trunc2(v1[0], v1[1]);
  u[3] = trunc2(v1[2], v1[3]);
  return __builtin_bit_cast(bf16x8, u);
}
// Weight frag: lane holds W[kt*32+g*8+b][ct*16+l15] (A-operand of swapped MFMA)
__device__ __forceinline__ bf16x8 bfrag_w(const float* W, int kt, int ct, int lane) {
  const float* p = W + (size_t)(kt * 32 + ((lane >> 4) * 8)) * 64 + ct * 16 + (lane & 15);
  bf16x8 r;
#pragma unroll
  for (int b = 0; b < 8; ++b) r[b] = (short)f2b_rtne(p[(size_t)b * 64]);
  return r;
}

// K1: h = x @ w_node + b_node ; x1b = bf16(h[:,:64]); sigxkb = bf16(sigmoid(h[:,64:]))
__global__ __launch_bounds__(128) void k_node_mlp(
    const float* __restrict__ x, const float* __restrict__ w_node,
    const float* __restrict__ b_node, ushort* __restrict__ x1b,
    ushort* __restrict__ sigxkb) {
  __shared__ float xs[H_DIM];
  int n = blockIdx.x;
  int c = threadIdx.x;
  xs[c] = x[(size_t)n * H_DIM + c];
  __syncthreads();
  float acc = b_node[c];
#pragma unroll 8
  for (int k = 0; k < H_DIM; ++k)
    acc = fmaf(xs[k], w_node[k * H_DIM + c], acc);
  if (c < C_DIM)
    x1b[(size_t)n * C_DIM + c] = f2b_rtne(acc);
  else
    sigxkb[(size_t)n * C_DIM + (c - C_DIM)] = f2b_rtne(sigmoid_f(acc));
}

// K2 v3: cji2 = silu(silu(cji@w_c1)@w_c2). Coalesced 16-row strips,
// swapped-operand MFMA, single LDS fence per strip, prefetched next strip.
__global__ __launch_bounds__(256, 3) void k_cji_mlp2(
    const float* __restrict__ cji, const float* __restrict__ w_c1,
    const float* __restrict__ w_c2, ushort* __restrict__ cji2) {
  __shared__ uint32 lds_all[4][2][16 * USTR];
  int lane = threadIdx.x & 63;
  int l15 = lane & 15, g = lane >> 4;
  int wid = (blockIdx.x * 256 + (int)threadIdx.x) >> 6;
  int nw = (gridDim.x * 256) >> 6;
  bf16x8 w1f[2][4], w2f[2][4];
#pragma unroll
  for (int kt = 0; kt < 2; ++kt)
#pragma unroll
    for (int ct = 0; ct < 4; ++ct) {
      w1f[kt][ct] = bfrag_w(w_c1, kt, ct, lane);
      w2f[kt][ct] = bfrag_w(w_c2, kt, ct, lane);
    }
  uint32* cji2u = (uint32*)cji2;
  const int nstrips = (E_EDGES * NORB) / 16;  // 56250
  f32x4 z = {0.f, 0.f, 0.f, 0.f};
  int s = wid;
  int parity = 0;
  f32x4 nv0, nv1, nv2, nv3;
  if (s < nstrips) {
    const float* ap = cji + (size_t)(s * 16 + l15) * 64 + g * 8;
    nv0 = *(const f32x4*)ap;
    nv1 = *(const f32x4*)(ap + 4);
    nv2 = *(const f32x4*)(ap + 32);
    nv3 = *(const f32x4*)(ap + 36);
  }
  while (s < nstrips) {
    f32x4 c0 = nv0, c1 = nv1, c2 = nv2, c3 = nv3;
    int sn = s + nw;
    if (sn < nstrips) {  // issue next-strip loads NOW; they stay in flight
      const float* np = cji + (size_t)(sn * 16 + l15) * 64 + g * 8;
      nv0 = *(const f32x4*)np;
      nv1 = *(const f32x4*)(np + 4);
      nv2 = *(const f32x4*)(np + 32);
      nv3 = *(const f32x4*)(np + 36);
    }
    uint32* lds = lds_all[threadIdx.x >> 6][parity];
    bf16x8 a0 = pack8v(c0, c1), a1 = pack8v(c2, c3);
    // layer 1 (swapped): lane -> data-row l15, channels ct*16+4g+r
#pragma unroll
    for (int ct = 0; ct < 4; ++ct) {
      f32x4 acc = mfma16(w1f[0][ct], a0, z);
      acc = mfma16(w1f[1][ct], a1, acc);
      uint32x2 p;
      p[0] = rtne2(silu_f(acc[0]), silu_f(acc[1]));
      p[1] = rtne2(silu_f(acc[2]), silu_f(acc[3]));
      *(uint32x2*)(lds + l15 * USTR + ct * 8 + 2 * g) = p;
    }
    LDS_FENCE();
    bf16x8 t0 = *(const bf16x8*)(lds + l15 * USTR + 4 * g);
    bf16x8 t1 = *(const bf16x8*)(lds + l15 * USTR + 16 + 4 * g);
    uint32* base = cji2u + (size_t)(s * 16 + l15) * 32;
#pragma unroll
    for (int ct = 0; ct < 4; ++ct) {
      f32x4 acc = mfma16(w2f[0][ct], t0, z);
      acc = mfma16(w2f[1][ct], t1, acc);
      uint32x2 p;
      p[0] = rtne2(silu_f(acc[0]), silu_f(acc[1]));
      p[1] = rtne2(silu_f(acc[2]), silu_f(acc[3]));
      *(uint32x2*)(base + ct * 8 + 2 * g) = p;
    }
    s = sn;
    parity ^= 1;
  }
}

// K2b: rbsum[e,h] = sum_d rb[e,d]*cutoff[e]*cji2[e,d,h]. Pure streaming.
__global__ __launch_bounds__(256) void k_rbsum(
    const ushort* __restrict__ cji2, const float* __restrict__ rb,
    const float* __restrict__ cutoff_w, float* __restrict__ rbsum) {
  int tid = blockIdx.x * 256 + threadIdx.x;
  int nth = gridDim.x * 256;
  const uint32x2* c2 = (const uint32x2*)cji2;  // 8B = 4 channels
  for (int it = tid; it < E_EDGES * 16; it += nth) {
    int e = it >> 4, cq = it & 15;
    float cw = cutoff_w[e];
    f32x4 acc = {0.f, 0.f, 0.f, 0.f};
    const uint32x2* p = c2 + (size_t)e * 9 * 16 + cq;
#pragma unroll
    for (int d = 0; d < NORB; ++d) {
      uint32x2 u = p[(size_t)d * 16];
      float w = rb[e * NORB + d] * cw;
      acc[0] = fmaf(w, __uint_as_float(u[0] << 16), acc[0]);
      acc[1] = fmaf(w, __uint_as_float(u[0] & 0xFFFF0000u), acc[1]);
      acc[2] = fmaf(w, __uint_as_float(u[1] << 16), acc[2]);
      acc[3] = fmaf(w, __uint_as_float(u[1] & 0xFFFF0000u), acc[3]);
    }
    *(f32x4*)(rbsum + (size_t)e * 64 + cq * 4) = acc;
  }
}

// K3: per-triplet gather + normalize + gate + atomic segment-sum
__global__ __launch_bounds__(256) void k_triplet(
    const ushort* __restrict__ cji2, const float* __restrict__ rb,
    const float* __restrict__ cutoff_w, const float* __restrict__ shb,
    const int* __restrict__ tri_idx_k, const int* __restrict__ edge_idx_kj,
    const int* __restrict__ edge_idx_ji, const ushort* __restrict__ sigxkb,
    float* __restrict__ agg) {
  int lane = threadIdx.x & 63;
  int wid = (blockIdx.x * 256 + (int)threadIdx.x) >> 6;
  int nw = (gridDim.x * 256) >> 6;
  for (int t = wid; t < T_TRI; t += nw) {
    int e = edge_idx_kj[t];
    float cw = cutoff_w[e];
    const ushort* crow = cji2 + (size_t)e * (NORB * C_DIM);
    float acc = 0.f;
#pragma unroll
    for (int d = 0; d < NORB; ++d) {
      float coeff = rb[e * NORB + d] * cw * shb[t * NORB + d];
      acc = fmaf(coeff, b2f(crow[d * C_DIM + lane]), acc);
    }
    float s = acc * acc;
#pragma unroll
    for (int m = 32; m >= 1; m >>= 1) s += __shfl_xor(s, m, 64);
    float scale = __builtin_amdgcn_rsqf(fmaxf(s, 1e-30f));
    int kn = tri_idx_k[t];
    float gxe = b2f(sigxkb[(size_t)kn * C_DIM + lane]);
    float val = acc * scale * gxe;
    int ej = edge_idx_ji[t];
    atomicAdd(&agg[(size_t)ej * C_DIM + lane], val);
  }
}

// K45: tbw = silu(silu(agg@w_t1+b_t1)@w_t2+b_t2) (in-reg);
//      lcao = normalize(rbsum*(1+tbw)) @ w_basis. Swapped-operand MFMA.
__global__ __launch_bounds__(256) void k_tbw_lcao(
    const float* __restrict__ agg, const float* __restrict__ w_t1,
    const float* __restrict__ b_t1, const float* __restrict__ w_t2,
    const float* __restrict__ b_t2, const float* __restrict__ rbsum,
    const float* __restrict__ w_basis, float* __restrict__ lcao) {
  __shared__ uint32 lds_all[4][2][16 * USTR];
  int lane = threadIdx.x & 63;
  int l15 = lane & 15, g = lane >> 4;
  uint32* lds0 = lds_all[threadIdx.x >> 6][0];
  uint32* lds1 = lds_all[threadIdx.x >> 6][1];
  int wid = (blockIdx.x * 256 + (int)threadIdx.x) >> 6;
  int nw = (gridDim.x * 256) >> 6;
  bf16x8 wt1[2][4], wt2[2][4], wb[2][4];
  float bt1v[4][4], bt2v[4][4];
#pragma unroll
  for (int ct = 0; ct < 4; ++ct) {
#pragma unroll
    for (int r = 0; r < 4; ++r) {
      bt1v[ct][r] = b_t1[ct * 16 + 4 * g + r];
      bt2v[ct][r] = b_t2[ct * 16 + 4 * g + r];
    }
#pragma unroll
    for (int kt = 0; kt < 2; ++kt) {
      wt1[kt][ct] = bfrag_w(w_t1, kt, ct, lane);
      wt2[kt][ct] = bfrag_w(w_t2, kt, ct, lane);
      wb[kt][ct] = bfrag_w(w_basis, kt, ct, lane);
    }
  }
  const int nblk = E_EDGES / 16;
  f32x4 z = {0.f, 0.f, 0.f, 0.f};
  for (int eb = wid; eb < nblk; eb += nw) {
    int e0 = eb * 16;
    const float* ap = agg + (size_t)(e0 + l15) * 64 + g * 8;
    bf16x8 a0 = pack8(ap), a1 = pack8(ap + 32);
#pragma unroll
    for (int ct = 0; ct < 4; ++ct) {
      f32x4 acc = mfma16(wt1[0][ct], a0, z);
      acc = mfma16(wt1[1][ct], a1, acc);
      uint32x2 p;
      p[0] = rtne2(silu_f(acc[0] + bt1v[ct][0]), silu_f(acc[1] + bt1v[ct][1]));
      p[1] = rtne2(silu_f(acc[2] + bt1v[ct][2]), silu_f(acc[3] + bt1v[ct][3]));
      *(uint32x2*)(lds0 + l15 * USTR + ct * 8 + 2 * g) = p;
    }
    LDS_FENCE();
    bf16x8 t0 = *(const bf16x8*)(lds0 + l15 * USTR + 4 * g);
    bf16x8 t1 = *(const bf16x8*)(lds0 + l15 * USTR + 16 + 4 * g);
    const float* rp = rbsum + (size_t)(e0 + l15) * 64 + 4 * g;
    f32x4 val[4];
    float ss = 0.f;
#pragma unroll
    for (int ct = 0; ct < 4; ++ct) {
      f32x4 acc = mfma16(wt2[0][ct], t0, z);
      acc = mfma16(wt2[1][ct], t1, acc);
      f32x4 q = *(const f32x4*)(rp + ct * 16);
      val[ct][0] = q[0] * (1.0f + silu_f(acc[0] + bt2v[ct][0]));
      val[ct][1] = q[1] * (1.0f + silu_f(acc[1] + bt2v[ct][1]));
      val[ct][2] = q[2] * (1.0f + silu_f(acc[2] + bt2v[ct][2]));
      val[ct][3] = q[3] * (1.0f + silu_f(acc[3] + bt2v[ct][3]));
      ss += val[ct][0] * val[ct][0] + val[ct][1] * val[ct][1] +
            val[ct][2] * val[ct][2] + val[ct][3] * val[ct][3];
    }
    ss += __shfl_xor(ss, 16, 64);
    ss += __shfl_xor(ss, 32, 64);
    float scale = __builtin_amdgcn_rsqf(fmaxf(ss, 1e-30f));
#pragma unroll
    for (int ct = 0; ct < 4; ++ct) {
      uint32x2 p;
      p[0] = rtne2(val[ct][0] * scale, val[ct][1] * scale);
      p[1] = rtne2(val[ct][2] * scale, val[ct][3] * scale);
      *(uint32x2*)(lds1 + l15 * USTR + ct * 8 + 2 * g) = p;
    }
    LDS_FENCE();
    bf16x8 n0 = *(const bf16x8*)(lds1 + l15 * USTR + 4 * g);
    bf16x8 n1 = *(const bf16x8*)(lds1 + l15 * USTR + 16 + 4 * g);
    float* lp = lcao + (size_t)(e0 + l15) * 64 + 4 * g;
#pragma unroll
    for (int ct = 0; ct < 4; ++ct) {
      f32x4 o = mfma16(wb[0][ct], n0, z);
      o = mfma16(wb[1][ct], n1, o);
      *(f32x4*)(lp + ct * 16) = o;
    }
  }
}

// K6: fnode = silu(silu([x1_i,x1_j]@w_n1+b_n1)@w_n2+b_n2);
//     msg = lcao*fnode; atomic scatter into nodeagg[idx_i].
__global__ __launch_bounds__(256) void k_msg_mfma(
    const ushort* __restrict__ x1b, const int* __restrict__ idx_i,
    const int* __restrict__ idx_j, const float* __restrict__ w_n1,
    const float* __restrict__ b_n1, const float* __restrict__ w_n2,
    const float* __restrict__ b_n2, const float* __restrict__ lcao,
    float* __restrict__ nodeagg) {
  __shared__ uint32 lds_all[4][16 * USTR];
  int lane = threadIdx.x & 63;
  int l15 = lane & 15, g = lane >> 4;
  uint32* lds = lds_all[threadIdx.x >> 6];
  int wid = (blockIdx.x * 256 + (int)threadIdx.x) >> 6;
  int nw = (gridDim.x * 256) >> 6;
  bf16x8 wn1f[4][4], wn2f[2][4];
  float bn1v[4][4], bn2v[4][4];
#pragma unroll
  for (int ct = 0; ct < 4; ++ct) {
#pragma unroll
    for (int r = 0; r < 4; ++r) {
      bn1v[ct][r] = b_n1[ct * 16 + 4 * g + r];
      bn2v[ct][r] = b_n2[ct * 16 + 4 * g + r];
    }
#pragma unroll
    for (int kt = 0; kt < 4; ++kt) wn1f[kt][ct] = bfrag_w(w_n1, kt, ct, lane);
#pragma unroll
    for (int kt = 0; kt < 2; ++kt) wn2f[kt][ct] = bfrag_w(w_n2, kt, ct, lane);
  }
  const int nblk = E_EDGES / 16;
  f32x4 z = {0.f, 0.f, 0.f, 0.f};
  for (int eb = wid; eb < nblk; eb += nw) {
    int er = eb * 16 + l15;
    int ii = idx_i[er], jj = idx_j[er];
    const uint32x4* pi = (const uint32x4*)(x1b + (size_t)ii * 64 + g * 8);
    const uint32x4* pj = (const uint32x4*)(x1b + (size_t)jj * 64 + g * 8);
    bf16x8 a0 = __builtin_bit_cast(bf16x8, pi[0]);
    bf16x8 a1 = __builtin_bit_cast(bf16x8, pi[2]);
    bf16x8 a2 = __builtin_bit_cast(bf16x8, pj[0]);
    bf16x8 a3 = __builtin_bit_cast(bf16x8, pj[2]);
#pragma unroll
    for (int ct = 0; ct < 4; ++ct) {
      f32x4 acc = mfma16(wn1f[0][ct], a0, z);
      acc = mfma16(wn1f[1][ct], a1, acc);
      acc = mfma16(wn1f[2][ct], a2, acc);
      acc = mfma16(wn1f[3][ct], a3, acc);
      uint32x2 p;
      p[0] = rtne2(silu_f(acc[0] + bn1v[ct][0]), silu_f(acc[1] + bn1v[ct][1]));
      p[1] = rtne2(silu_f(acc[2] + bn1v[ct][2]), silu_f(acc[3] + bn1v[ct][3]));
      *(uint32x2*)(lds + l15 * USTR + ct * 8 + 2 * g) = p;
    }
    LDS_FENCE();
    bf16x8 t0 = *(const bf16x8*)(lds + l15 * USTR + 4 * g);
    bf16x8 t1 = *(const bf16x8*)(lds + l15 * USTR + 16 + 4 * g);
    const float* lp = lcao + (size_t)er * 64 + 4 * g;
    float* np = nodeagg + (size_t)ii * 64 + 4 * g;
#pragma unroll
    for (int ct = 0; ct < 4; ++ct) {
      f32x4 acc = mfma16(wn2f[0][ct], t0, z);
      acc = mfma16(wn2f[1][ct], t1, acc);
      f32x4 q = *(const f32x4*)(lp + ct * 16);
      atomicAdd(np + ct * 16 + 0, q[0] * silu_f(acc[0] + bn2v[ct][0]));
      atomicAdd(np + ct * 16 + 1, q[1] * silu_f(acc[1] + bn2v[ct][1]));
      atomicAdd(np + ct * 16 + 2, q[2] * silu_f(acc[2] + bn2v[ct][2]));
      atomicAdd(np + ct * 16 + 3, q[3] * silu_f(acc[3] + bn2v[ct][3]));
    }
  }
}

// K7: out = x + nodeagg @ w_out
__global__ __launch_bounds__(256) void k_out(
    const float* __restrict__ x, const float* __restrict__ nodeagg,
    const float* __restrict__ w_out, float* __restrict__ out) {
  int lane = threadIdx.x & 63;
  int wid = (blockIdx.x * 256 + (int)threadIdx.x) >> 6;
  int nw = (gridDim.x * 256) >> 6;
  float wo0[64], wo1[64];
#pragma unroll
  for (int k = 0; k < 64; ++k) wo0[k] = w_out[k * H_DIM + lane];
#pragma unroll
  for (int k = 0; k < 64; ++k) wo1[k] = w_out[k * H_DIM + 64 + lane];
  for (int n = wid; n < N_NODES; n += nw) {
    float v = nodeagg[(size_t)n * 64 + lane];
    float a0 = 0.f, a1 = 0.f;
#pragma unroll
    for (int k = 0; k < 64; ++k) {
      float a = rl(v, k);
      a0 = fmaf(a, wo0[k], a0);
      a1 = fmaf(a, wo1[k], a1);
    }
    out[(size_t)n * H_DIM + lane] = x[(size_t)n * H_DIM + lane] + a0;
    out[(size_t)n * H_DIM + 64 + lane] = x[(size_t)n * H_DIM + 64 + lane] + a1;
  }
}

extern "C" void kernel_launch(void* const* d_in, const int* in_sizes, int n_in,
                              void* d_out, int out_size, void* d_ws, size_t ws_size,
                              hipStream_t stream) {
  const float* x         = (const float*)d_in[0];
  const float* cji       = (const float*)d_in[1];
  const float* cutoff_w  = (const float*)d_in[2];
  const float* rb        = (const float*)d_in[3];
  const float* shb       = (const float*)d_in[4];
  const int*   idx_i     = (const int*)d_in[5];
  const int*   idx_j     = (const int*)d_in[6];
  const int*   tri_idx_k = (const int*)d_in[7];
  const int*   e_kj      = (const int*)d_in[8];
  const int*   e_ji      = (const int*)d_in[9];
  const float* w_node    = (const float*)d_in[10];
  const float* b_node    = (const float*)d_in[11];
  const float* w_c1      = (const float*)d_in[12];
  const float* w_c2      = (const float*)d_in[13];
  const float* w_t1      = (const float*)d_in[14];
  const float* b_t1      = (const float*)d_in[15];
  const float* w_t2      = (const float*)d_in[16];
  const float* b_t2      = (const float*)d_in[17];
  const float* w_basis   = (const float*)d_in[18];
  const float* w_n1      = (const float*)d_in[19];
  const float* b_n1      = (const float*)d_in[20];
  const float* w_n2      = (const float*)d_in[21];
  const float* b_n2      = (const float*)d_in[22];
  const float* w_out     = (const float*)d_in[23];
  float* out = (float*)d_out;

  char* ws = (char*)d_ws;
  ushort* x1b    = (ushort*)(ws + 0);            //   1,280,000 B
  ushort* sigxkb = (ushort*)(ws + 1280000);      //   1,280,000 B
  ushort* cji2   = (ushort*)(ws + 2560000);      // 115,200,000 B
  float*  aggbuf = (float*)(ws + 117760000);     //  25,600,000 B
  float*  rbsum  = (float*)(ws + 143360000);     //  25,600,000 B
  float*  lcao   = (float*)(ws + 168960000);     //  25,600,000 B
  float*  nodeagg= (float*)(ws + 194560000);     //   2,560,000 B

  hipMemsetAsync(aggbuf, 0, (size_t)6400000 * sizeof(float), stream);
  hipMemsetAsync(nodeagg, 0, (size_t)640000 * sizeof(float), stream);

  k_node_mlp<<<N_NODES, 128, 0, stream>>>(x, w_node, b_node, x1b, sigxkb);
  k_cji_mlp2<<<2048, 256, 0, stream>>>(cji, w_c1, w_c2, cji2);
  k_rbsum<<<2048, 256, 0, stream>>>(cji2, rb, cutoff_w, rbsum);
  k_triplet<<<2048, 256, 0, stream>>>(cji2, rb, cutoff_w, shb, tri_idx_k, e_kj,
                                      e_ji, sigxkb, aggbuf);
  k_tbw_lcao<<<784, 256, 0, stream>>>(aggbuf, w_t1, b_t1, w_t2, b_t2, rbsum,
                                      w_basis, lcao);
  k_msg_mfma<<<1024, 256, 0, stream>>>(x1b, idx_i, idx_j, w_n1, b_n1, w_n2,
                                       b_n2, lcao, nodeagg);
  k_out<<<256, 256, 0, stream>>>(x, nodeagg, w_out, out);
}

// Round 6
// 309.439 us; speedup vs baseline: 1.1791x; 1.1396x over previous
//
#include <hip/hip_runtime.h>
#include <math.h>

typedef __attribute__((ext_vector_type(8))) short bf16x8;
typedef __attribute__((ext_vector_type(4))) float f32x4;
typedef __attribute__((ext_vector_type(4))) unsigned int uint32x4;
typedef unsigned int uint32;
typedef unsigned short ushort;

#define N_NODES 10000
#define E_EDGES 100000
#define T_TRI   200000
#define NORB    9
#define H_DIM   128
#define C_DIM   64
#define LSTR    68   // padded LDS row stride (floats): 272B, 16B-aligned, 2-way banks

__device__ __forceinline__ ushort f2b_rtne(float f) {
  uint32 u = __float_as_uint(f);
  u += 0x7FFFu + ((u >> 16) & 1u);
  return (ushort)(u >> 16);
}
__device__ __forceinline__ uint32 rtne2(float a, float b) {  // low=a, high=b
  uint32 ua = __float_as_uint(a), ub = __float_as_uint(b);
  ua += 0x7FFFu + ((ua >> 16) & 1u);
  ub += 0x7FFFu + ((ub >> 16) & 1u);
  return (ua >> 16) | (ub & 0xFFFF0000u);
}
__device__ __forceinline__ uint32 trunc2(float a, float b) {
  return (__float_as_uint(a) >> 16) | (__float_as_uint(b) & 0xFFFF0000u);
}
__device__ __forceinline__ float b2f(ushort u) {
  return __uint_as_float(((uint32)u) << 16);
}
__device__ __forceinline__ float blo(uint32 u) {
  return __uint_as_float(u << 16);
}
__device__ __forceinline__ float bhi(uint32 u) {
  return __uint_as_float(u & 0xFFFF0000u);
}
__device__ __forceinline__ float silu_f(float x) {
  return x * __builtin_amdgcn_rcpf(1.0f + __expf(-x));
}
__device__ __forceinline__ float sigmoid_f(float x) {
  return __builtin_amdgcn_rcpf(1.0f + __expf(-x));
}
__device__ __forceinline__ float rl(float v, int k) {
  return __uint_as_float(__builtin_amdgcn_readlane(__float_as_uint(v), k));
}
__device__ __forceinline__ f32x4 mfma16(bf16x8 a, bf16x8 b, f32x4 c) {
  return __builtin_amdgcn_mfma_f32_16x16x32_bf16(a, b, c, 0, 0, 0);
}
#define LDS_FENCE() asm volatile("s_waitcnt lgkmcnt(0)" ::: "memory")

// trunc-pack 8 consecutive f32 (16B-aligned) into a bf16x8 frag
__device__ __forceinline__ bf16x8 pack8(const float* p) {
  f32x4 v0 = *(const f32x4*)p;
  f32x4 v1 = *(const f32x4*)(p + 4);
  uint32x4 u;
  u[0] = trunc2(v0[0], v0[1]);
  u[1] = trunc2(v0[2], v0[3]);
  u[2] = trunc2(v1[0], v1[1]);
  u[3] = trunc2(v1[2], v1[3]);
  return __builtin_bit_cast(bf16x8, u);
}
// B-frag (RTNE, done once at kernel start) for W[K][64] row-major
__device__ __forceinline__ bf16x8 bfrag_w(const float* W, int kt, int ct, int lane) {
  const float* p = W + (size_t)(kt * 32 + ((lane >> 4) * 8)) * 64 + ct * 16 + (lane & 15);
  bf16x8 r;
#pragma unroll
  for (int b = 0; b < 8; ++b) r[b] = (short)f2b_rtne(p[(size_t)b * 64]);
  return r;
}

// K1: h = x @ w_node + b_node ; x1b = bf16(h[:,:64]); sigxkb = bf16(sigmoid(h[:,64:]))
__global__ __launch_bounds__(128) void k_node_mlp(
    const float* __restrict__ x, const float* __restrict__ w_node,
    const float* __restrict__ b_node, ushort* __restrict__ x1b,
    ushort* __restrict__ sigxkb) {
  __shared__ float xs[H_DIM];
  int n = blockIdx.x;
  int c = threadIdx.x;
  xs[c] = x[(size_t)n * H_DIM + c];
  __syncthreads();
  float acc = b_node[c];
#pragma unroll 8
  for (int k = 0; k < H_DIM; ++k)
    acc = fmaf(xs[k], w_node[k * H_DIM + c], acc);
  if (c < C_DIM)
    x1b[(size_t)n * C_DIM + c] = f2b_rtne(acc);
  else
    sigxkb[(size_t)n * C_DIM + (c - C_DIM)] = f2b_rtne(sigmoid_f(acc));
}

// K2: cji2 = silu(silu(cji @ w_c1) @ w_c2), 900000 rows, bf16 MFMA, bf16 out.
__global__ __launch_bounds__(256) void k_cji_mlp_mfma(
    const float* __restrict__ cji, const float* __restrict__ w_c1,
    const float* __restrict__ w_c2, ushort* __restrict__ cji2) {
  __shared__ __align__(16) float lds_all[4][16 * LSTR];
  int lane = threadIdx.x & 63;
  float* lds = lds_all[threadIdx.x >> 6];
  int wid = (blockIdx.x * 256 + (int)threadIdx.x) >> 6;
  int nw = (gridDim.x * 256) >> 6;
  bf16x8 w1f[2][4], w2f[2][4];
#pragma unroll
  for (int kt = 0; kt < 2; ++kt)
#pragma unroll
    for (int ct = 0; ct < 4; ++ct) {
      w1f[kt][ct] = bfrag_w(w_c1, kt, ct, lane);
      w2f[kt][ct] = bfrag_w(w_c2, kt, ct, lane);
    }
  const int nstrips = (E_EDGES * NORB) / 16;  // 56250
  int l15 = lane & 15, g = lane >> 4;
  int wrow = g * 4, wcol = l15;
  f32x4 z = {0.f, 0.f, 0.f, 0.f};
  for (int s = wid; s < nstrips; s += nw) {
    const float* ap = cji + (size_t)(s * 16 + l15) * 64 + g * 8;
    bf16x8 a0 = pack8(ap), a1 = pack8(ap + 32);
#pragma unroll
    for (int ct = 0; ct < 4; ++ct) {
      f32x4 acc = mfma16(a0, w1f[0][ct], z);
      acc = mfma16(a1, w1f[1][ct], acc);
#pragma unroll
      for (int r = 0; r < 4; ++r)
        lds[(wrow + r) * LSTR + ct * 16 + wcol] = silu_f(acc[r]);
    }
    LDS_FENCE();
    bf16x8 t0 = pack8(lds + l15 * LSTR + g * 8);
    bf16x8 t1 = pack8(lds + l15 * LSTR + 32 + g * 8);
#pragma unroll
    for (int ct = 0; ct < 4; ++ct) {
      f32x4 acc = mfma16(t0, w2f[0][ct], z);
      acc = mfma16(t1, w2f[1][ct], acc);
#pragma unroll
      for (int r = 0; r < 4; ++r)
        lds[(wrow + r) * LSTR + ct * 16 + wcol] = silu_f(acc[r]);
    }
    LDS_FENCE();
    const float* lp = lds + l15 * LSTR + g * 16;
    f32x4 v0 = *(const f32x4*)lp;
    f32x4 v1 = *(const f32x4*)(lp + 4);
    f32x4 v2 = *(const f32x4*)(lp + 8);
    f32x4 v3 = *(const f32x4*)(lp + 12);
    uint32x4 o0, o1;
    o0[0] = rtne2(v0[0], v0[1]); o0[1] = rtne2(v0[2], v0[3]);
    o0[2] = rtne2(v1[0], v1[1]); o0[3] = rtne2(v1[2], v1[3]);
    o1[0] = rtne2(v2[0], v2[1]); o1[1] = rtne2(v2[2], v2[3]);
    o1[2] = rtne2(v3[0], v3[1]); o1[3] = rtne2(v3[2], v3[3]);
    uint32x4* dst = (uint32x4*)(cji2 + (size_t)(s * 16 + l15) * 64 + g * 16);
    dst[0] = o0;
    dst[1] = o1;
  }
}

// K3 v2: TWO triplets per wave. Lanes 0-31 -> triplet 2*tb, lanes 32-63 ->
// triplet 2*tb+1. Each lane gathers a uint32 (2 bf16 channels) per orbital:
// halves the VMEM instruction count of the gather vs the 2B-per-lane version.
__global__ __launch_bounds__(256) void k_triplet2(
    const ushort* __restrict__ cji2, const float* __restrict__ rb,
    const float* __restrict__ cutoff_w, const float* __restrict__ shb,
    const int* __restrict__ tri_idx_k, const int* __restrict__ edge_idx_kj,
    const int* __restrict__ edge_idx_ji, const ushort* __restrict__ sigxkb,
    float* __restrict__ agg) {
  int lane = threadIdx.x & 63;
  int half = lane >> 5;   // which triplet of the pair
  int l = lane & 31;      // channel-pair index (2 channels per lane)
  int wid = (blockIdx.x * 256 + (int)threadIdx.x) >> 6;
  int nw = (gridDim.x * 256) >> 6;
  const uint32* c2 = (const uint32*)cji2;
  const uint32* sx = (const uint32*)sigxkb;
  for (int tb = wid; tb < T_TRI / 2; tb += nw) {
    int t = tb * 2 + half;
    int e = edge_idx_kj[t];
    float cw = cutoff_w[e];
    const uint32* crow = c2 + (size_t)e * (NORB * 32);
    float a0 = 0.f, a1 = 0.f;
#pragma unroll
    for (int d = 0; d < NORB; ++d) {
      uint32 u = crow[d * 32 + l];
      float coeff = rb[e * NORB + d] * cw * shb[t * NORB + d];
      a0 = fmaf(coeff, blo(u), a0);
      a1 = fmaf(coeff, bhi(u), a1);
    }
    float ss = a0 * a0 + a1 * a1;
#pragma unroll
    for (int m = 16; m >= 1; m >>= 1) ss += __shfl_xor(ss, m, 64);  // within half
    float scale = __builtin_amdgcn_rsqf(fmaxf(ss, 1e-30f));
    int kn = tri_idx_k[t];
    uint32 gx = sx[(size_t)kn * 32 + l];
    float v0 = a0 * scale * blo(gx);
    float v1 = a1 * scale * bhi(gx);
    int ej = edge_idx_ji[t];
    float* ap = agg + (size_t)ej * C_DIM + 2 * l;
    atomicAdd(ap, v0);
    atomicAdd(ap + 1, v1);
  }
}

// K4+K5 fused: tbw = MLP(agg) (kept in LDS); lcao = normalize((1+tbw)*sum_d rb_w*cji2) @ w_basis
__global__ __launch_bounds__(256) void k_tbw_lcao(
    const float* __restrict__ agg, const float* __restrict__ w_t1,
    const float* __restrict__ b_t1, const float* __restrict__ w_t2,
    const float* __restrict__ b_t2, const ushort* __restrict__ cji2,
    const float* __restrict__ rb, const float* __restrict__ cutoff_w,
    const float* __restrict__ w_basis, float* __restrict__ lcao) {
  __shared__ __align__(16) float lds_all[4][16 * LSTR];
  int lane = threadIdx.x & 63;
  float* lds = lds_all[threadIdx.x >> 6];
  int wid = (blockIdx.x * 256 + (int)threadIdx.x) >> 6;
  int nw = (gridDim.x * 256) >> 6;
  bf16x8 wt1[2][4], wt2[2][4], wb[2][4];
  float bt1[4], bt2[4];
  int l15 = lane & 15, g = lane >> 4;
#pragma unroll
  for (int ct = 0; ct < 4; ++ct) {
    bt1[ct] = b_t1[ct * 16 + l15];
    bt2[ct] = b_t2[ct * 16 + l15];
#pragma unroll
    for (int kt = 0; kt < 2; ++kt) {
      wt1[kt][ct] = bfrag_w(w_t1, kt, ct, lane);
      wt2[kt][ct] = bfrag_w(w_t2, kt, ct, lane);
      wb[kt][ct] = bfrag_w(w_basis, kt, ct, lane);
    }
  }
  const int nstrips = E_EDGES / 16;  // 6250
  int wrow = g * 4, wcol = l15;
  f32x4 z = {0.f, 0.f, 0.f, 0.f};
  for (int s = wid; s < nstrips; s += nw) {
    const float* ap = agg + (size_t)(s * 16 + l15) * 64 + g * 8;
    bf16x8 a0 = pack8(ap), a1 = pack8(ap + 32);
#pragma unroll
    for (int ct = 0; ct < 4; ++ct) {
      f32x4 acc = mfma16(a0, wt1[0][ct], z);
      acc = mfma16(a1, wt1[1][ct], acc);
#pragma unroll
      for (int r = 0; r < 4; ++r)
        lds[(wrow + r) * LSTR + ct * 16 + wcol] = silu_f(acc[r] + bt1[ct]);
    }
    LDS_FENCE();
    bf16x8 t0 = pack8(lds + l15 * LSTR + g * 8);
    bf16x8 t1 = pack8(lds + l15 * LSTR + 32 + g * 8);
    LDS_FENCE();
#pragma unroll
    for (int ct = 0; ct < 4; ++ct) {
      f32x4 acc = mfma16(t0, wt2[0][ct], z);
      acc = mfma16(t1, wt2[1][ct], acc);
#pragma unroll
      for (int r = 0; r < 4; ++r)
        lds[(wrow + r) * LSTR + ct * 16 + wcol] = silu_f(acc[r] + bt2[ct]);  // tbw tile
    }
    LDS_FENCE();
    // per-edge orbital contraction, gate by (1+tbw), normalize -> overwrite tile rows
    for (int ee = 0; ee < 16; ++ee) {
      int e = s * 16 + ee;
      float cw = cutoff_w[e];
      const ushort* crow = cji2 + (size_t)e * (NORB * C_DIM);
      float acc = 0.f;
#pragma unroll
      for (int d = 0; d < NORB; ++d)
        acc = fmaf(rb[e * NORB + d] * cw, b2f(crow[d * C_DIM + lane]), acc);
      acc *= (1.0f + lds[ee * LSTR + lane]);
      float ss = acc * acc;
#pragma unroll
      for (int m = 32; m >= 1; m >>= 1) ss += __shfl_xor(ss, m, 64);
      float scale = __builtin_amdgcn_rsqf(fmaxf(ss, 1e-30f));
      lds[ee * LSTR + lane] = acc * scale;
    }
    LDS_FENCE();
    bf16x8 n0 = pack8(lds + l15 * LSTR + g * 8);
    bf16x8 n1 = pack8(lds + l15 * LSTR + 32 + g * 8);
    LDS_FENCE();
    f32x4 o[4];
#pragma unroll
    for (int ct = 0; ct < 4; ++ct) {
      o[ct] = mfma16(n0, wb[0][ct], z);
      o[ct] = mfma16(n1, wb[1][ct], o[ct]);
#pragma unroll
      for (int r = 0; r < 4; ++r)
        lds[(wrow + r) * LSTR + ct * 16 + wcol] = o[ct][r];
    }
    LDS_FENCE();
    const float* lp = lds + l15 * LSTR + g * 16;
    f32x4* dst = (f32x4*)(lcao + (size_t)(s * 16 + l15) * 64 + g * 16);
    dst[0] = *(const f32x4*)lp;
    dst[1] = *(const f32x4*)(lp + 4);
    dst[2] = *(const f32x4*)(lp + 8);
    dst[3] = *(const f32x4*)(lp + 12);
  }
}

// K6: fnode = silu(silu([x1_i,x1_j] @ w_n1 + b_n1) @ w_n2 + b_n2);
//     msg = lcao * fnode; atomic scatter into nodeagg[idx_i].
__global__ __launch_bounds__(256) void k_msg_mfma(
    const ushort* __restrict__ x1b, const int* __restrict__ idx_i,
    const int* __restrict__ idx_j, const float* __restrict__ w_n1,
    const float* __restrict__ b_n1, const float* __restrict__ w_n2,
    const float* __restrict__ b_n2, const float* __restrict__ lcao,
    float* __restrict__ nodeagg) {
  __shared__ __align__(16) float lds_all[4][16 * LSTR];
  int lane = threadIdx.x & 63;
  float* lds = lds_all[threadIdx.x >> 6];
  int wid = (blockIdx.x * 256 + (int)threadIdx.x) >> 6;
  int nw = (gridDim.x * 256) >> 6;
  bf16x8 wn1f[4][4], wn2f[2][4];
  float bn1[4], bn2[4];
  int l15 = lane & 15, g = lane >> 4;
#pragma unroll
  for (int ct = 0; ct < 4; ++ct) {
    bn1[ct] = b_n1[ct * 16 + l15];
    bn2[ct] = b_n2[ct * 16 + l15];
#pragma unroll
    for (int kt = 0; kt < 4; ++kt) wn1f[kt][ct] = bfrag_w(w_n1, kt, ct, lane);
#pragma unroll
    for (int kt = 0; kt < 2; ++kt) wn2f[kt][ct] = bfrag_w(w_n2, kt, ct, lane);
  }
  const int nstrips = E_EDGES / 16;
  int wrow = g * 4, wcol = l15;
  f32x4 z = {0.f, 0.f, 0.f, 0.f};
  for (int s = wid; s < nstrips; s += nw) {
    int er = s * 16 + l15;
    int ii = idx_i[er], jj = idx_j[er];
    const uint32x4* pi = (const uint32x4*)(x1b + (size_t)ii * 64 + g * 8);
    const uint32x4* pj = (const uint32x4*)(x1b + (size_t)jj * 64 + g * 8);
    bf16x8 a0 = __builtin_bit_cast(bf16x8, pi[0]);
    bf16x8 a1 = __builtin_bit_cast(bf16x8, pi[2]);  // +32 elems = +2 uint32x4
    bf16x8 a2 = __builtin_bit_cast(bf16x8, pj[0]);
    bf16x8 a3 = __builtin_bit_cast(bf16x8, pj[2]);
#pragma unroll
    for (int ct = 0; ct < 4; ++ct) {
      f32x4 acc = mfma16(a0, wn1f[0][ct], z);
      acc = mfma16(a1, wn1f[1][ct], acc);
      acc = mfma16(a2, wn1f[2][ct], acc);
      acc = mfma16(a3, wn1f[3][ct], acc);
#pragma unroll
      for (int r = 0; r < 4; ++r)
        lds[(wrow + r) * LSTR + ct * 16 + wcol] = silu_f(acc[r] + bn1[ct]);
    }
    LDS_FENCE();
    bf16x8 t0 = pack8(lds + l15 * LSTR + g * 8);
    bf16x8 t1 = pack8(lds + l15 * LSTR + 32 + g * 8);
    f32x4 acc2[4];
#pragma unroll
    for (int ct = 0; ct < 4; ++ct) {
      acc2[ct] = mfma16(t0, wn2f[0][ct], z);
      acc2[ct] = mfma16(t1, wn2f[1][ct], acc2[ct]);
    }
#pragma unroll
    for (int r = 0; r < 4; ++r) {
      int ge = s * 16 + wrow + r;
      int ni = idx_i[ge];
#pragma unroll
      for (int ct = 0; ct < 4; ++ct) {
        float f = silu_f(acc2[ct][r] + bn2[ct]);
        float m = lcao[(size_t)ge * 64 + ct * 16 + l15] * f;
        atomicAdd(&nodeagg[(size_t)ni * 64 + ct * 16 + l15], m);
      }
    }
  }
}

// K7: out = x + nodeagg @ w_out
__global__ __launch_bounds__(256) void k_out(
    const float* __restrict__ x, const float* __restrict__ nodeagg,
    const float* __restrict__ w_out, float* __restrict__ out) {
  int lane = threadIdx.x & 63;
  int wid = (blockIdx.x * 256 + (int)threadIdx.x) >> 6;
  int nw = (gridDim.x * 256) >> 6;
  float wo0[64], wo1[64];
#pragma unroll
  for (int k = 0; k < 64; ++k) wo0[k] = w_out[k * H_DIM + lane];
#pragma unroll
  for (int k = 0; k < 64; ++k) wo1[k] = w_out[k * H_DIM + 64 + lane];
  for (int n = wid; n < N_NODES; n += nw) {
    float v = nodeagg[(size_t)n * 64 + lane];
    float a0 = 0.f, a1 = 0.f;
#pragma unroll
    for (int k = 0; k < 64; ++k) {
      float a = rl(v, k);
      a0 = fmaf(a, wo0[k], a0);
      a1 = fmaf(a, wo1[k], a1);
    }
    out[(size_t)n * H_DIM + lane] = x[(size_t)n * H_DIM + lane] + a0;
    out[(size_t)n * H_DIM + 64 + lane] = x[(size_t)n * H_DIM + 64 + lane] + a1;
  }
}

extern "C" void kernel_launch(void* const* d_in, const int* in_sizes, int n_in,
                              void* d_out, int out_size, void* d_ws, size_t ws_size,
                              hipStream_t stream) {
  const float* x         = (const float*)d_in[0];
  const float* cji       = (const float*)d_in[1];
  const float* cutoff_w  = (const float*)d_in[2];
  const float* rb        = (const float*)d_in[3];
  const float* shb       = (const float*)d_in[4];
  const int*   idx_i     = (const int*)d_in[5];
  const int*   idx_j     = (const int*)d_in[6];
  const int*   tri_idx_k = (const int*)d_in[7];
  const int*   e_kj      = (const int*)d_in[8];
  const int*   e_ji      = (const int*)d_in[9];
  const float* w_node    = (const float*)d_in[10];
  const float* b_node    = (const float*)d_in[11];
  const float* w_c1      = (const float*)d_in[12];
  const float* w_c2      = (const float*)d_in[13];
  const float* w_t1      = (const float*)d_in[14];
  const float* b_t1      = (const float*)d_in[15];
  const float* w_t2      = (const float*)d_in[16];
  const float* b_t2      = (const float*)d_in[17];
  const float* w_basis   = (const float*)d_in[18];
  const float* w_n1      = (const float*)d_in[19];
  const float* b_n1      = (const float*)d_in[20];
  const float* w_n2      = (const float*)d_in[21];
  const float* b_n2      = (const float*)d_in[22];
  const float* w_out     = (const float*)d_in[23];
  float* out = (float*)d_out;

  char* ws = (char*)d_ws;
  ushort* x1b    = (ushort*)(ws + 0);            //   1,280,000 B
  ushort* sigxkb = (ushort*)(ws + 1280000);      //   1,280,000 B
  ushort* cji2   = (ushort*)(ws + 2560000);      // 115,200,000 B
  float*  aggbuf = (float*)(ws + 117760000);     //  25,600,000 B
  float*  lcao   = (float*)(ws + 143360000);     //  25,600,000 B
  float*  nodeagg= (float*)(ws + 168960000);     //   2,560,000 B

  hipMemsetAsync(aggbuf, 0, (size_t)6400000 * sizeof(float), stream);
  hipMemsetAsync(nodeagg, 0, (size_t)640000 * sizeof(float), stream);

  k_node_mlp<<<N_NODES, 128, 0, stream>>>(x, w_node, b_node, x1b, sigxkb);
  k_cji_mlp_mfma<<<2048, 256, 0, stream>>>(cji, w_c1, w_c2, cji2);
  k_triplet2<<<2048, 256, 0, stream>>>(cji2, rb, cutoff_w, shb, tri_idx_k, e_kj,
                                       e_ji, sigxkb, aggbuf);
  k_tbw_lcao<<<1024, 256, 0, stream>>>(aggbuf, w_t1, b_t1, w_t2, b_t2, cji2,
                                       rb, cutoff_w, w_basis, lcao);
  k_msg_mfma<<<1024, 256, 0, stream>>>(x1b, idx_i, idx_j, w_n1, b_n1, w_n2,
                                       b_n2, lcao, nodeagg);
  k_out<<<256, 256, 0, stream>>>(x, nodeagg, w_out, out);
}